// Round 6
// baseline (278.768 us; speedup 1.0000x reference)
//
#include <hip/hip_runtime.h>

// Problem constants
#define NP 2048          // B*H1*W1 points
#define CD 768           // channels
#define NSPLIT 6         // channel splits for d2 partials (128 ch each)
#define NJOBS 528        // 136 XX-tri + 136 YY-tri + 256 XY tiles
#define MMD_GAMMA 0.00065f

typedef short bf16frag __attribute__((ext_vector_type(8)));
typedef float f32x4 __attribute__((ext_vector_type(4)));

#define GLD16(g, l)  __builtin_amdgcn_global_load_lds(                      \
    (const __attribute__((address_space(1))) void*)(g),                     \
    (__attribute__((address_space(3))) void*)(l), 16, 0, 0)

static __device__ inline unsigned short f2bf(float v) {
    union { float f; unsigned u; } a; a.f = v;
    unsigned r = a.u + 0x7fffu + ((a.u >> 16) & 1u);
    return (unsigned short)(r >> 16);
}
static __device__ inline float bf2f(unsigned short h) {
    union { unsigned u; float f; } a; a.u = ((unsigned)h) << 16;
    return a.f;
}

// ---------------------------------------------------------------------------
// Transpose x (B,C,32,32) -> X rows + fold bf16 split pack of X.
__global__ void k_transpose_x(const float* __restrict__ x, float* __restrict__ X,
                              unsigned short* __restrict__ Xhi, unsigned short* __restrict__ Xlo) {
    __shared__ float tile[64][33];
    int bx = blockIdx.x;
    int c0 = blockIdx.y * 64;
    int b = bx >> 5, h1 = bx & 31;
    int tid = threadIdx.x;
    const float* src = x + (size_t)(b * 768 + c0) * 1024 + h1 * 32;
    #pragma unroll
    for (int p = 0; p < 8; ++p) {
        int cl = p * 8 + (tid >> 5);
        int w1 = tid & 31;
        tile[cl][w1] = src[(size_t)cl * 1024 + w1];
    }
    __syncthreads();
    int n0 = bx * 32;
    #pragma unroll
    for (int p = 0; p < 8; ++p) {
        int w1 = p * 4 + (tid >> 6);
        int c  = tid & 63;
        float v = tile[c][w1];
        size_t o = (size_t)(n0 + w1) * CD + c0 + c;
        X[o] = v;
        unsigned short h = f2bf(v);
        Xhi[o] = h;
        Xlo[o] = f2bf(v - bf2f(h));
    }
}

// ---------------------------------------------------------------------------
__global__ __launch_bounds__(256, 4)
void k_d2_partial(const float* __restrict__ x, const float* __restrict__ y,
                  double* __restrict__ d2p) {
    __shared__ double red[8][32][4];
    int bxh = blockIdx.x;
    int cs  = blockIdx.y;
    int b = bxh >> 7, h = bxh & 127;
    int h1 = h >> 2, i = h & 3;
    int tid = threadIdx.x;
    int w1 = tid & 31, cg = tid >> 5;
    int c0 = cs * 128 + cg;
    const float* yp = y + ((size_t)(b * 768 + c0) * 128 + h) * 128 + 4 * w1;
    const float* xp = x + (size_t)(b * 768 + c0) * 1024 + h1 * 32 + w1;
    double a0 = 0.0, a1 = 0.0, a2 = 0.0, a3 = 0.0;
    #pragma unroll 8
    for (int k = 0; k < 16; ++k) {
        float4 yv = *(const float4*)yp;
        float xv = *xp;
        double xd = (double)xv;
        double d0 = xd - (double)yv.x;
        double d1 = xd - (double)yv.y;
        double d2_ = xd - (double)yv.z;
        double d3 = xd - (double)yv.w;
        a0 += d0 * d0; a1 += d1 * d1; a2 += d2_ * d2_; a3 += d3 * d3;
        yp += (size_t)8 * 16384;
        xp += (size_t)8 * 1024;
    }
    red[cg][w1][0] = a0; red[cg][w1][1] = a1;
    red[cg][w1][2] = a2; red[cg][w1][3] = a3;
    __syncthreads();
    if (tid < 128) {
        int w = tid >> 2, j = tid & 3;
        double s = 0.0;
        #pragma unroll
        for (int g = 0; g < 8; ++g) s += red[g][w][j];
        int n = b * 1024 + h1 * 32 + w;
        d2p[((size_t)cs * NP + n) * 16 + i * 4 + j] = s;
    }
}

// ---------------------------------------------------------------------------
// Per-point argmax over 16 candidates (same fp64 sum order as before ->
// bit-identical to np path; strict > = first-max tie-break).
__global__ void k_argmax(const double* __restrict__ d2p, int* __restrict__ idx) {
    int n = blockIdx.x * 256 + threadIdx.x;
    double s[16];
    #pragma unroll
    for (int k = 0; k < 16; ++k) s[k] = 0.0;
    for (int cs = 0; cs < NSPLIT; ++cs) {
        #pragma unroll
        for (int k = 0; k < 16; ++k) s[k] += d2p[((size_t)cs * NP + n) * 16 + k];
    }
    double best = s[0]; int bi = 0;
    #pragma unroll
    for (int k = 1; k < 16; ++k) if (s[k] > best) { best = s[k]; bi = k; }
    idx[n] = bi;
}

// ---------------------------------------------------------------------------
// Coalesced gather + bf16 pack of selected y rows + b2 partial norms.
// Block (b*32+h1, cs): stages y[b, c, 4h1..4h1+3, 0..127] (2KB/channel,
// contiguous) for 8 channels at a time; 32 points extract their selected
// element from LDS. y is read exactly once, fully coalesced.
__global__ __launch_bounds__(256, 4)
void k_gather_pack_y(const float* __restrict__ y, const int* __restrict__ idx,
                     unsigned short* __restrict__ Yhi, unsigned short* __restrict__ Ylo,
                     float* __restrict__ b2f) {
    __shared__ float ytile[8][520];     // 520 pad: extract lands 2-way max
    __shared__ int sOff[32];
    __shared__ float sqred[32][8];
    int bh = blockIdx.x;                // b*32 + h1
    int cs = blockIdx.y;                // 0..11, 64 channels each
    int b = bh >> 5, h1 = bh & 31;
    int tid = threadIdx.x;
    if (tid < 32) {
        int id = idx[b * 1024 + h1 * 32 + tid];
        sOff[tid] = (id >> 2) * 128 + 4 * tid + (id & 3);
    }
    __syncthreads();
    int c_loc = tid & 7, n_loc = tid >> 3;
    int ch_s = tid >> 5, part = tid & 31;
    int off = sOff[n_loc];
    int n = b * 1024 + h1 * 32 + n_loc;
    float sq = 0.f;
    for (int kt = 0; kt < 8; ++kt) {
        int c0 = cs * 64 + kt * 8;
        __syncthreads();
        const float* src = y + ((size_t)(b * 768 + c0 + ch_s) * 128 + 4 * h1) * 128;
        #pragma unroll
        for (int u = 0; u < 4; ++u)
            *(float4*)&ytile[ch_s][u * 128 + part * 4] = *(const float4*)(src + u * 128 + part * 4);
        __syncthreads();
        float v = ytile[c_loc][off];
        unsigned short h = f2bf(v);
        size_t o = (size_t)n * CD + c0 + c_loc;
        Yhi[o] = h;
        Ylo[o] = f2bf(v - bf2f(h));
        sq += v * v;
    }
    sqred[n_loc][c_loc] = sq;
    __syncthreads();
    if (tid < 32) {
        float s = 0.f;
        #pragma unroll
        for (int g = 0; g < 8; ++g) s += sqred[tid][g];
        atomicAdd(&b2f[b * 1024 + h1 * 32 + tid], s);
    }
}

// ---------------------------------------------------------------------------
__global__ void k_row_norm(const float* __restrict__ M, float* __restrict__ out) {
    __shared__ double red[256];
    int n = blockIdx.x, tid = threadIdx.x;
    double s = 0.0;
    for (int c = tid; c < CD; c += 256) {
        float v = M[(size_t)n * CD + c];
        s += (double)v * (double)v;
    }
    red[tid] = s;
    __syncthreads();
    for (int st = 128; st > 0; st >>= 1) {
        if (tid < st) red[tid] += red[tid + st];
        __syncthreads();
    }
    if (tid == 0) out[n] = (float)red[0];
}

// ---------------------------------------------------------------------------
// Persistent MFMA Gram + exp-sum: 512 blocks pull 528 tile-jobs via atomic
// counter (dynamic balance; 4 blocks/CU co-resident). Split-bf16 K''=2304:
// A=[hi|lo|hi], B=[hi|hi|lo]. XOR-swizzled LDS + global_load_lds w=16.
// NOTE: unsigned job-id guard — a poisoned/negative counter exits instead of
// computing OOB tile addresses (suspected round-5 crash path).
__global__ __launch_bounds__(256, 4)
void k_mmd_mfma(const unsigned short* __restrict__ Xhi, const unsigned short* __restrict__ Xlo,
                const unsigned short* __restrict__ Yhi, const unsigned short* __restrict__ Ylo,
                const float* __restrict__ a2, const float* __restrict__ b2,
                double* __restrict__ accg, int* __restrict__ counter) {
    __shared__ unsigned short As[128 * 64];
    __shared__ unsigned short Bs[128 * 64];
    __shared__ float red[256];
    __shared__ int sjob;

    int tid = threadIdx.x;
    int lane = tid & 63;
    int wv = tid >> 6;
    int wr = wv >> 1, wc = wv & 1;
    int m = lane & 15, q = lane >> 4;
    int lrow = lane >> 3, lchunk = lane & 7;

    for (;;) {
        if (tid == 0) sjob = atomicAdd(counter, 1);
        __syncthreads();
        int id = sjob;
        if ((unsigned)id >= (unsigned)NJOBS) break;   // also exits on negative/poison

        int z, bx, by;
        double w = 1.0;
        if (id < 272) {
            z = (id < 136) ? 0 : 1;
            if (id >= 136) id -= 136;
            int r = 0;
            while (id >= 16 - r) { id -= 16 - r; ++r; }
            by = r; bx = r + id;
            if (bx != by) w = 2.0;
        } else {
            z = 2; id -= 272;
            bx = id & 15; by = id >> 4;
        }
        const unsigned short* AH = (z == 1) ? Yhi : Xhi;
        const unsigned short* AL = (z == 1) ? Ylo : Xlo;
        const unsigned short* BH = (z == 0) ? Xhi : Yhi;
        const unsigned short* BL = (z == 0) ? Xlo : Ylo;
        const float* na = (z == 1) ? b2 : a2;
        const float* nb = (z == 0) ? a2 : b2;
        int i0 = by * 128, j0 = bx * 128;

        f32x4 acc[4][4] = {};

        for (int kk = 0; kk < 2304; kk += 64) {
            int p = (kk >= 1536) ? 2 : (kk >= 768 ? 1 : 0);
            int kc = kk - p * 768;
            const unsigned short* Asrc = (p == 1) ? AL : AH;
            const unsigned short* Bsrc = (p == 2) ? BL : BH;
            __syncthreads();
            #pragma unroll
            for (int s = 0; s < 4; ++s) {
                int r0 = s * 32 + wv * 8;
                int r  = r0 + lrow;
                int cg = lchunk ^ (r & 7);
                GLD16(Asrc + (size_t)(i0 + r) * CD + kc + cg * 8, &As[r0 * 64]);
                GLD16(Bsrc + (size_t)(j0 + r) * CD + kc + cg * 8, &Bs[r0 * 64]);
            }
            __syncthreads();
            #pragma unroll
            for (int s16 = 0; s16 < 2; ++s16) {
                bf16frag af[4], bg[4];
                #pragma unroll
                for (int t = 0; t < 4; ++t) {
                    int ra = wr * 64 + t * 16 + m;
                    int rb = wc * 64 + t * 16 + m;
                    af[t] = *(const bf16frag*)&As[ra * 64 + ((s16 * 4 + q) ^ (m & 7)) * 8];
                    bg[t] = *(const bf16frag*)&Bs[rb * 64 + ((s16 * 4 + q) ^ (m & 7)) * 8];
                }
                #pragma unroll
                for (int ti = 0; ti < 4; ++ti)
                    #pragma unroll
                    for (int tj = 0; tj < 4; ++tj)
                        acc[ti][tj] = __builtin_amdgcn_mfma_f32_16x16x32_bf16(
                            af[ti], bg[tj], acc[ti][tj], 0, 0, 0);
            }
        }

        float s = 0.0f;
        #pragma unroll
        for (int ti = 0; ti < 4; ++ti) {
            #pragma unroll
            for (int r = 0; r < 4; ++r) {
                int i = i0 + wr * 64 + ti * 16 + q * 4 + r;
                float ai = na[i];
                #pragma unroll
                for (int tj = 0; tj < 4; ++tj) {
                    int j = j0 + wc * 64 + tj * 16 + m;
                    float d = ai + nb[j] - 2.0f * acc[ti][tj][r];
                    d = fmaxf(d, 0.0f);
                    s += expf(-MMD_GAMMA * d);
                }
            }
        }
        red[tid] = s;
        __syncthreads();
        for (int st = 128; st > 0; st >>= 1) {
            if (tid < st) red[tid] += red[tid + st];
            __syncthreads();
        }
        if (tid == 0) atomicAdd(&accg[z], w * (double)red[0]);
        __syncthreads();
    }
}

// ---------------------------------------------------------------------------
__global__ void k_finalize(const double* __restrict__ acc, float* __restrict__ out) {
    const double inv = 1.0 / ((double)NP * (double)NP);
    out[0] = (float)((acc[0] + acc[1] - 2.0 * acc[2]) * inv);
}

extern "C" void kernel_launch(void* const* d_in, const int* in_sizes, int n_in,
                              void* d_out, int out_size, void* d_ws, size_t ws_size,
                              hipStream_t stream) {
    const float* x = (const float*)d_in[0];
    const float* y = (const float*)d_in[1];
    float* out = (float*)d_out;

    char* ws = (char*)d_ws;
    double* acc     = (double*)ws;                    // [0,24)
    int*    counter = (int*)(ws + 64);                // 4B
    float*  b2f     = (float*)(ws + 4096);            // 8KB
    int*    idx     = (int*)(ws + 12288);             // 8KB
    double* d2p     = (double*)(ws + 32768);          // 1.5 MB
    float*  X       = (float*)(ws + 32768 + 1605632);
    float*  a2      = X + (size_t)NP * CD;
    unsigned short* Xhi = (unsigned short*)(a2 + NP);
    unsigned short* Xlo = Xhi + (size_t)NP * CD;
    unsigned short* Yhi = Xlo + (size_t)NP * CD;
    unsigned short* Ylo = Yhi + (size_t)NP * CD;

    hipMemsetAsync(ws, 0, 12288, stream);             // acc + counter + b2f
    k_transpose_x<<<dim3(64, 12), 256, 0, stream>>>(x, X, Xhi, Xlo);
    k_d2_partial<<<dim3(256, NSPLIT), 256, 0, stream>>>(x, y, d2p);
    k_argmax<<<NP / 256, 256, 0, stream>>>(d2p, idx);
    k_gather_pack_y<<<dim3(64, 12), 256, 0, stream>>>(y, idx, Yhi, Ylo, b2f);
    k_row_norm<<<NP, 256, 0, stream>>>(X, a2);
    k_mmd_mfma<<<512, 256, 0, stream>>>(Xhi, Xlo, Yhi, Ylo, a2, b2f, acc, counter);
    k_finalize<<<1, 1, 0, stream>>>(acc, out);
}

// Round 7
// 236.624 us; speedup vs baseline: 1.1781x; 1.1781x over previous
//
#include <hip/hip_runtime.h>

// Problem constants
#define NP 2048          // B*H1*W1 points
#define CD 768           // channels
#define NSPLIT 6         // channel splits for d2 partials (128 ch each)
#define NJOBS 528        // 136 XX-tri + 136 YY-tri + 256 XY tiles
#define MMD_GAMMA 0.00065f

typedef short bf16frag __attribute__((ext_vector_type(8)));
typedef float f32x4 __attribute__((ext_vector_type(4)));

#define GLD16(g, l)  __builtin_amdgcn_global_load_lds(                      \
    (const __attribute__((address_space(1))) void*)(g),                     \
    (__attribute__((address_space(3))) void*)(l), 16, 0, 0)

static __device__ inline unsigned short f2bf(float v) {
    union { float f; unsigned u; } a; a.f = v;
    unsigned r = a.u + 0x7fffu + ((a.u >> 16) & 1u);
    return (unsigned short)(r >> 16);
}
static __device__ inline float bf2f(unsigned short h) {
    union { unsigned u; float f; } a; a.u = ((unsigned)h) << 16;
    return a.f;
}

// ---------------------------------------------------------------------------
// Transpose x (B,C,32,32) -> X rows + bf16 split pack + a2 partial norms
// (f32 atomics; 12 partials/point -> ~1e-7 relative error on the output).
__global__ void k_transpose_x(const float* __restrict__ x, float* __restrict__ X,
                              unsigned short* __restrict__ Xhi, unsigned short* __restrict__ Xlo,
                              float* __restrict__ a2f) {
    __shared__ float tile[64][33];
    __shared__ float sqred[8][32];
    int bx = blockIdx.x;
    int c0 = blockIdx.y * 64;
    int b = bx >> 5, h1 = bx & 31;
    int tid = threadIdx.x;
    const float* src = x + (size_t)(b * 768 + c0) * 1024 + h1 * 32;
    #pragma unroll
    for (int p = 0; p < 8; ++p) {
        int cl = p * 8 + (tid >> 5);
        int w1 = tid & 31;
        tile[cl][w1] = src[(size_t)cl * 1024 + w1];
    }
    __syncthreads();
    int n0 = bx * 32;
    #pragma unroll
    for (int p = 0; p < 8; ++p) {
        int w1 = p * 4 + (tid >> 6);
        int c  = tid & 63;
        float v = tile[c][w1];
        size_t o = (size_t)(n0 + w1) * CD + c0 + c;
        X[o] = v;
        unsigned short h = f2bf(v);
        Xhi[o] = h;
        Xlo[o] = f2bf(v - bf2f(h));
    }
    // partial |x|^2 for this 64-channel slice
    {
        int w1 = tid & 31, cseg = tid >> 5;
        float s = 0.f;
        #pragma unroll
        for (int u = 0; u < 8; ++u) {
            float v = tile[cseg * 8 + u][w1];
            s += v * v;
        }
        sqred[cseg][w1] = s;
    }
    __syncthreads();
    if (tid < 32) {
        float s = 0.f;
        #pragma unroll
        for (int g = 0; g < 8; ++g) s += sqred[g][tid];
        atomicAdd(&a2f[n0 + tid], s);
    }
}

// ---------------------------------------------------------------------------
__global__ __launch_bounds__(256, 4)
void k_d2_partial(const float* __restrict__ x, const float* __restrict__ y,
                  double* __restrict__ d2p) {
    __shared__ double red[8][32][4];
    int bxh = blockIdx.x;
    int cs  = blockIdx.y;
    int b = bxh >> 7, h = bxh & 127;
    int h1 = h >> 2, i = h & 3;
    int tid = threadIdx.x;
    int w1 = tid & 31, cg = tid >> 5;
    int c0 = cs * 128 + cg;
    const float* yp = y + ((size_t)(b * 768 + c0) * 128 + h) * 128 + 4 * w1;
    const float* xp = x + (size_t)(b * 768 + c0) * 1024 + h1 * 32 + w1;
    double a0 = 0.0, a1 = 0.0, a2 = 0.0, a3 = 0.0;
    #pragma unroll 8
    for (int k = 0; k < 16; ++k) {
        float4 yv = *(const float4*)yp;
        float xv = *xp;
        double xd = (double)xv;
        double d0 = xd - (double)yv.x;
        double d1 = xd - (double)yv.y;
        double d2_ = xd - (double)yv.z;
        double d3 = xd - (double)yv.w;
        a0 += d0 * d0; a1 += d1 * d1; a2 += d2_ * d2_; a3 += d3 * d3;
        yp += (size_t)8 * 16384;
        xp += (size_t)8 * 1024;
    }
    red[cg][w1][0] = a0; red[cg][w1][1] = a1;
    red[cg][w1][2] = a2; red[cg][w1][3] = a3;
    __syncthreads();
    if (tid < 128) {
        int w = tid >> 2, j = tid & 3;
        double s = 0.0;
        #pragma unroll
        for (int g = 0; g < 8; ++g) s += red[g][w][j];
        int n = b * 1024 + h1 * 32 + w;
        d2p[((size_t)cs * NP + n) * 16 + i * 4 + j] = s;
    }
}

// ---------------------------------------------------------------------------
// Fused argmax + coalesced gather + bf16 pack + b2 partial norms.
// tid<32 recompute their point's argmax from d2p with the SAME fp64 sum
// order as before (cs 0..5, then strict-> first-max) -> bit-identical idx.
__global__ __launch_bounds__(256, 4)
void k_gather_pack_y(const float* __restrict__ y, const double* __restrict__ d2p,
                     unsigned short* __restrict__ Yhi, unsigned short* __restrict__ Ylo,
                     float* __restrict__ b2f) {
    __shared__ float ytile[8][520];     // 520 pad: extract lands 2-way max
    __shared__ int sOff[32];
    __shared__ float sqred[32][8];
    int bh = blockIdx.x;                // b*32 + h1
    int cs = blockIdx.y;                // 0..11, 64 channels each
    int b = bh >> 5, h1 = bh & 31;
    int tid = threadIdx.x;
    if (tid < 32) {
        int n = b * 1024 + h1 * 32 + tid;
        double s[16];
        #pragma unroll
        for (int k = 0; k < 16; ++k) s[k] = 0.0;
        for (int c = 0; c < NSPLIT; ++c) {
            #pragma unroll
            for (int k = 0; k < 16; ++k) s[k] += d2p[((size_t)c * NP + n) * 16 + k];
        }
        double best = s[0]; int bi = 0;
        #pragma unroll
        for (int k = 1; k < 16; ++k) if (s[k] > best) { best = s[k]; bi = k; }
        sOff[tid] = (bi >> 2) * 128 + 4 * tid + (bi & 3);
    }
    __syncthreads();
    int c_loc = tid & 7, n_loc = tid >> 3;
    int ch_s = tid >> 5, part = tid & 31;
    int off = sOff[n_loc];
    int n = b * 1024 + h1 * 32 + n_loc;
    float sq = 0.f;
    for (int kt = 0; kt < 8; ++kt) {
        int c0 = cs * 64 + kt * 8;
        __syncthreads();
        const float* src = y + ((size_t)(b * 768 + c0 + ch_s) * 128 + 4 * h1) * 128;
        #pragma unroll
        for (int u = 0; u < 4; ++u)
            *(float4*)&ytile[ch_s][u * 128 + part * 4] = *(const float4*)(src + u * 128 + part * 4);
        __syncthreads();
        float v = ytile[c_loc][off];
        unsigned short h = f2bf(v);
        size_t o = (size_t)n * CD + c0 + c_loc;
        Yhi[o] = h;
        Ylo[o] = f2bf(v - bf2f(h));
        sq += v * v;
    }
    sqred[n_loc][c_loc] = sq;
    __syncthreads();
    if (tid < 32) {
        float s = 0.f;
        #pragma unroll
        for (int g = 0; g < 8; ++g) s += sqred[tid][g];
        atomicAdd(&b2f[b * 1024 + h1 * 32 + tid], s);
    }
}

// ---------------------------------------------------------------------------
// MFMA Gram + exp-sum (round-4 known-good config: static 528 blocks).
// Split-bf16 K''=2304: A=[hi|lo|hi], B=[hi|hi|lo]. XOR-swizzled LDS +
// global_load_lds w=16. Grid: 136 XX-tri + 136 YY-tri + 256 XY.
__global__ __launch_bounds__(256, 2)
void k_mmd_mfma(const unsigned short* __restrict__ Xhi, const unsigned short* __restrict__ Xlo,
                const unsigned short* __restrict__ Yhi, const unsigned short* __restrict__ Ylo,
                const float* __restrict__ a2, const float* __restrict__ b2,
                double* __restrict__ accg) {
    __shared__ unsigned short As[128 * 64];
    __shared__ unsigned short Bs[128 * 64];
    __shared__ float red[256];

    int id = blockIdx.x;
    int z, bx, by;
    double w = 1.0;
    if (id < 272) {
        z = (id < 136) ? 0 : 1;
        if (id >= 136) id -= 136;
        int r = 0;
        while (id >= 16 - r) { id -= 16 - r; ++r; }
        by = r; bx = r + id;
        if (bx != by) w = 2.0;
    } else {
        z = 2; id -= 272;
        bx = id & 15; by = id >> 4;
    }
    const unsigned short* AH = (z == 1) ? Yhi : Xhi;
    const unsigned short* AL = (z == 1) ? Ylo : Xlo;
    const unsigned short* BH = (z == 0) ? Xhi : Yhi;
    const unsigned short* BL = (z == 0) ? Xlo : Ylo;
    const float* na = (z == 1) ? b2 : a2;
    const float* nb = (z == 0) ? a2 : b2;
    int i0 = by * 128, j0 = bx * 128;

    int tid = threadIdx.x;
    int lane = tid & 63;
    int wv = tid >> 6;
    int wr = wv >> 1, wc = wv & 1;
    int m = lane & 15, q = lane >> 4;
    int lrow = lane >> 3, lchunk = lane & 7;

    f32x4 acc[4][4] = {};

    for (int kk = 0; kk < 2304; kk += 64) {
        int p = (kk >= 1536) ? 2 : (kk >= 768 ? 1 : 0);
        int kc = kk - p * 768;
        const unsigned short* Asrc = (p == 1) ? AL : AH;
        const unsigned short* Bsrc = (p == 2) ? BL : BH;
        __syncthreads();
        #pragma unroll
        for (int s = 0; s < 4; ++s) {
            int r0 = s * 32 + wv * 8;
            int r  = r0 + lrow;
            int cg = lchunk ^ (r & 7);
            GLD16(Asrc + (size_t)(i0 + r) * CD + kc + cg * 8, &As[r0 * 64]);
            GLD16(Bsrc + (size_t)(j0 + r) * CD + kc + cg * 8, &Bs[r0 * 64]);
        }
        __syncthreads();
        #pragma unroll
        for (int s16 = 0; s16 < 2; ++s16) {
            bf16frag af[4], bg[4];
            #pragma unroll
            for (int t = 0; t < 4; ++t) {
                int ra = wr * 64 + t * 16 + m;
                int rb = wc * 64 + t * 16 + m;
                af[t] = *(const bf16frag*)&As[ra * 64 + ((s16 * 4 + q) ^ (m & 7)) * 8];
                bg[t] = *(const bf16frag*)&Bs[rb * 64 + ((s16 * 4 + q) ^ (m & 7)) * 8];
            }
            #pragma unroll
            for (int ti = 0; ti < 4; ++ti)
                #pragma unroll
                for (int tj = 0; tj < 4; ++tj)
                    acc[ti][tj] = __builtin_amdgcn_mfma_f32_16x16x32_bf16(
                        af[ti], bg[tj], acc[ti][tj], 0, 0, 0);
        }
    }

    float s = 0.0f;
    #pragma unroll
    for (int ti = 0; ti < 4; ++ti) {
        #pragma unroll
        for (int r = 0; r < 4; ++r) {
            int i = i0 + wr * 64 + ti * 16 + q * 4 + r;
            float ai = na[i];
            #pragma unroll
            for (int tj = 0; tj < 4; ++tj) {
                int j = j0 + wc * 64 + tj * 16 + m;
                float d = ai + nb[j] - 2.0f * acc[ti][tj][r];
                d = fmaxf(d, 0.0f);
                s += expf(-MMD_GAMMA * d);
            }
        }
    }
    red[tid] = s;
    __syncthreads();
    for (int st = 128; st > 0; st >>= 1) {
        if (tid < st) red[tid] += red[tid + st];
        __syncthreads();
    }
    if (tid == 0) atomicAdd(&accg[z], w * (double)red[0]);
}

// ---------------------------------------------------------------------------
__global__ void k_finalize(const double* __restrict__ acc, float* __restrict__ out) {
    const double inv = 1.0 / ((double)NP * (double)NP);
    out[0] = (float)((acc[0] + acc[1] - 2.0 * acc[2]) * inv);
}

extern "C" void kernel_launch(void* const* d_in, const int* in_sizes, int n_in,
                              void* d_out, int out_size, void* d_ws, size_t ws_size,
                              hipStream_t stream) {
    const float* x = (const float*)d_in[0];
    const float* y = (const float*)d_in[1];
    float* out = (float*)d_out;

    char* ws = (char*)d_ws;
    double* acc = (double*)ws;                        // [0,24)
    float*  b2f = (float*)(ws + 4096);                // 8KB
    float*  a2f = (float*)(ws + 12288);               // 8KB
    double* d2p = (double*)(ws + 32768);              // 1.5 MB
    float*  X   = (float*)(ws + 32768 + 1605632);
    unsigned short* Xhi = (unsigned short*)(X + (size_t)NP * CD);
    unsigned short* Xlo = Xhi + (size_t)NP * CD;
    unsigned short* Yhi = Xlo + (size_t)NP * CD;
    unsigned short* Ylo = Yhi + (size_t)NP * CD;

    hipMemsetAsync(ws, 0, 20480, stream);             // acc + b2f + a2f
    k_transpose_x<<<dim3(64, 12), 256, 0, stream>>>(x, X, Xhi, Xlo, a2f);
    k_d2_partial<<<dim3(256, NSPLIT), 256, 0, stream>>>(x, y, d2p);
    k_gather_pack_y<<<dim3(64, 12), 256, 0, stream>>>(y, d2p, Yhi, Ylo, b2f);
    k_mmd_mfma<<<NJOBS, 256, 0, stream>>>(Xhi, Xlo, Yhi, Ylo, a2f, b2f, acc);
    k_finalize<<<1, 1, 0, stream>>>(acc, out);
}

// Round 8
// 229.620 us; speedup vs baseline: 1.2140x; 1.0305x over previous
//
#include <hip/hip_runtime.h>

// Problem constants
#define NP 2048          // B*H1*W1 points
#define CD 768           // channels
#define NSPLIT 6         // channel splits for d2 partials (128 ch each)
#define NJOBS 528        // 136 XX-tri + 136 YY-tri + 256 XY tiles
#define MMD_GAMMA 0.00065f

typedef short bf16frag __attribute__((ext_vector_type(8)));
typedef float f32x4 __attribute__((ext_vector_type(4)));

#define GLD16(g, l)  __builtin_amdgcn_global_load_lds(                      \
    (const __attribute__((address_space(1))) void*)(g),                     \
    (__attribute__((address_space(3))) void*)(l), 16, 0, 0)

static __device__ inline unsigned short f2bf(float v) {
    union { float f; unsigned u; } a; a.f = v;
    unsigned r = a.u + 0x7fffu + ((a.u >> 16) & 1u);
    return (unsigned short)(r >> 16);
}
static __device__ inline float bf2f(unsigned short h) {
    union { unsigned u; float f; } a; a.u = ((unsigned)h) << 16;
    return a.f;
}

// ---------------------------------------------------------------------------
// Transpose x (B,C,32,32) -> X rows + bf16 split pack + a2 partial norms.
__global__ void k_transpose_x(const float* __restrict__ x, float* __restrict__ X,
                              unsigned short* __restrict__ Xhi, unsigned short* __restrict__ Xlo,
                              float* __restrict__ a2f) {
    __shared__ float tile[64][33];
    __shared__ float sqred[8][32];
    int bx = blockIdx.x;
    int c0 = blockIdx.y * 64;
    int b = bx >> 5, h1 = bx & 31;
    int tid = threadIdx.x;
    const float* src = x + (size_t)(b * 768 + c0) * 1024 + h1 * 32;
    #pragma unroll
    for (int p = 0; p < 8; ++p) {
        int cl = p * 8 + (tid >> 5);
        int w1 = tid & 31;
        tile[cl][w1] = src[(size_t)cl * 1024 + w1];
    }
    __syncthreads();
    int n0 = bx * 32;
    #pragma unroll
    for (int p = 0; p < 8; ++p) {
        int w1 = p * 4 + (tid >> 6);
        int c  = tid & 63;
        float v = tile[c][w1];
        size_t o = (size_t)(n0 + w1) * CD + c0 + c;
        X[o] = v;
        unsigned short h = f2bf(v);
        Xhi[o] = h;
        Xlo[o] = f2bf(v - bf2f(h));
    }
    {
        int w1 = tid & 31, cseg = tid >> 5;
        float s = 0.f;
        #pragma unroll
        for (int u = 0; u < 8; ++u) {
            float v = tile[cseg * 8 + u][w1];
            s += v * v;
        }
        sqred[cseg][w1] = s;
    }
    __syncthreads();
    if (tid < 32) {
        float s = 0.f;
        #pragma unroll
        for (int g = 0; g < 8; ++g) s += sqred[g][tid];
        atomicAdd(&a2f[n0 + tid], s);
    }
}

// ---------------------------------------------------------------------------
__global__ __launch_bounds__(256, 4)
void k_d2_partial(const float* __restrict__ x, const float* __restrict__ y,
                  double* __restrict__ d2p) {
    __shared__ double red[8][32][4];
    int bxh = blockIdx.x;
    int cs  = blockIdx.y;
    int b = bxh >> 7, h = bxh & 127;
    int h1 = h >> 2, i = h & 3;
    int tid = threadIdx.x;
    int w1 = tid & 31, cg = tid >> 5;
    int c0 = cs * 128 + cg;
    const float* yp = y + ((size_t)(b * 768 + c0) * 128 + h) * 128 + 4 * w1;
    const float* xp = x + (size_t)(b * 768 + c0) * 1024 + h1 * 32 + w1;
    double a0 = 0.0, a1 = 0.0, a2 = 0.0, a3 = 0.0;
    #pragma unroll 8
    for (int k = 0; k < 16; ++k) {
        float4 yv = *(const float4*)yp;
        float xv = *xp;
        double xd = (double)xv;
        double d0 = xd - (double)yv.x;
        double d1 = xd - (double)yv.y;
        double d2_ = xd - (double)yv.z;
        double d3 = xd - (double)yv.w;
        a0 += d0 * d0; a1 += d1 * d1; a2 += d2_ * d2_; a3 += d3 * d3;
        yp += (size_t)8 * 16384;
        xp += (size_t)8 * 1024;
    }
    red[cg][w1][0] = a0; red[cg][w1][1] = a1;
    red[cg][w1][2] = a2; red[cg][w1][3] = a3;
    __syncthreads();
    if (tid < 128) {
        int w = tid >> 2, j = tid & 3;
        double s = 0.0;
        #pragma unroll
        for (int g = 0; g < 8; ++g) s += red[g][w][j];
        int n = b * 1024 + h1 * 32 + w;
        d2p[((size_t)cs * NP + n) * 16 + i * 4 + j] = s;
    }
}

// ---------------------------------------------------------------------------
// Fused argmax + coalesced gather + bf16 pack + b2 partial norms.
__global__ __launch_bounds__(256, 4)
void k_gather_pack_y(const float* __restrict__ y, const double* __restrict__ d2p,
                     unsigned short* __restrict__ Yhi, unsigned short* __restrict__ Ylo,
                     float* __restrict__ b2f) {
    __shared__ float ytile[8][520];
    __shared__ int sOff[32];
    __shared__ float sqred[32][8];
    int bh = blockIdx.x;                // b*32 + h1
    int cs = blockIdx.y;                // 0..11, 64 channels each
    int b = bh >> 5, h1 = bh & 31;
    int tid = threadIdx.x;
    if (tid < 32) {
        int n = b * 1024 + h1 * 32 + tid;
        double s[16];
        #pragma unroll
        for (int k = 0; k < 16; ++k) s[k] = 0.0;
        for (int c = 0; c < NSPLIT; ++c) {
            #pragma unroll
            for (int k = 0; k < 16; ++k) s[k] += d2p[((size_t)c * NP + n) * 16 + k];
        }
        double best = s[0]; int bi = 0;
        #pragma unroll
        for (int k = 1; k < 16; ++k) if (s[k] > best) { best = s[k]; bi = k; }
        sOff[tid] = (bi >> 2) * 128 + 4 * tid + (bi & 3);
    }
    __syncthreads();
    int c_loc = tid & 7, n_loc = tid >> 3;
    int ch_s = tid >> 5, part = tid & 31;
    int off = sOff[n_loc];
    int n = b * 1024 + h1 * 32 + n_loc;
    float sq = 0.f;
    for (int kt = 0; kt < 8; ++kt) {
        int c0 = cs * 64 + kt * 8;
        __syncthreads();
        const float* src = y + ((size_t)(b * 768 + c0 + ch_s) * 128 + 4 * h1) * 128;
        #pragma unroll
        for (int u = 0; u < 4; ++u)
            *(float4*)&ytile[ch_s][u * 128 + part * 4] = *(const float4*)(src + u * 128 + part * 4);
        __syncthreads();
        float v = ytile[c_loc][off];
        unsigned short h = f2bf(v);
        size_t o = (size_t)n * CD + c0 + c_loc;
        Yhi[o] = h;
        Ylo[o] = f2bf(v - bf2f(h));
        sq += v * v;
    }
    sqred[n_loc][c_loc] = sq;
    __syncthreads();
    if (tid < 32) {
        float s = 0.f;
        #pragma unroll
        for (int g = 0; g < 8; ++g) s += sqred[tid][g];
        atomicAdd(&b2f[b * 1024 + h1 * 32 + tid], s);
    }
}

// ---------------------------------------------------------------------------
// MFMA Gram + exp-sum, 2-term split: Gram = (hi_a + lo_a) . hi_b = a . hi_b.
// Per 32-channel window: A-tile = [hi32|lo32] (128x64 bf16), B-tile = [hi32]
// (128x32, staged once, frags reused for both K-halves). XOR swizzles keep
// all LDS access 2-way max. Grid: 136 XX-tri + 136 YY-tri + 256 XY = 528.
__global__ __launch_bounds__(256, 3)
void k_mmd_mfma(const unsigned short* __restrict__ Xhi, const unsigned short* __restrict__ Xlo,
                const unsigned short* __restrict__ Yhi, const unsigned short* __restrict__ Ylo,
                const float* __restrict__ a2, const float* __restrict__ b2,
                double* __restrict__ accg) {
    __shared__ unsigned short As[128 * 64];   // 16 KB
    __shared__ unsigned short Bs[128 * 32];   // 8 KB
    __shared__ float red[256];

    int id = blockIdx.x;
    int z, bx, by;
    double w = 1.0;
    if (id < 272) {
        z = (id < 136) ? 0 : 1;
        if (id >= 136) id -= 136;
        int r = 0;
        while (id >= 16 - r) { id -= 16 - r; ++r; }
        by = r; bx = r + id;
        if (bx != by) w = 2.0;
    } else {
        z = 2; id -= 272;
        bx = id & 15; by = id >> 4;
    }
    const unsigned short* AH = (z == 1) ? Yhi : Xhi;
    const unsigned short* AL = (z == 1) ? Ylo : Xlo;
    const unsigned short* BH = (z == 0) ? Xhi : Yhi;
    const float* na = (z == 1) ? b2 : a2;
    const float* nb = (z == 0) ? a2 : b2;
    int i0 = by * 128, j0 = bx * 128;

    int tid = threadIdx.x;
    int lane = tid & 63;
    int wv = tid >> 6;
    int wr = wv >> 1, wc = wv & 1;
    int m = lane & 15, q = lane >> 4;
    int lrow = lane >> 3, lchunk = lane & 7;   // A staging: 8 rows x 8 chunks
    int lrowB = lane >> 2, lchunkB = lane & 3; // B staging: 16 rows x 4 chunks

    f32x4 acc[4][4] = {};

    for (int wnd = 0; wnd < 24; ++wnd) {
        int c0 = wnd * 32;
        __syncthreads();
        // A: 128 rows x 64 bf16 = [hi(32ch) | lo(32ch)], chunk c holds
        // global chunk c^(r&7) (chunks 0-3 -> hi, 4-7 -> lo, post-XOR).
        #pragma unroll
        for (int s = 0; s < 4; ++s) {
            int r0 = s * 32 + wv * 8;
            int r  = r0 + lrow;
            int cg = lchunk ^ (r & 7);
            const unsigned short* srcA =
                (cg < 4 ? AH : AL) + (size_t)(i0 + r) * CD + c0 + (cg & 3) * 8;
            GLD16(srcA, &As[r0 * 64]);
        }
        // B: 128 rows x 32 bf16 (hi only), chunk c holds global chunk
        // c^((r>>1)&3): with the 64B row stride this spreads 8 consecutive
        // rows over 8 distinct 4-bank windows -> 2-way max.
        #pragma unroll
        for (int s = 0; s < 2; ++s) {
            int r0 = s * 64 + wv * 16;
            int r  = r0 + lrowB;
            int cg = lchunkB ^ ((r >> 1) & 3);
            GLD16(BH + (size_t)(j0 + r) * CD + c0 + cg * 8, &Bs[r0 * 32]);
        }
        __syncthreads();
        bf16frag bg[4];
        #pragma unroll
        for (int t = 0; t < 4; ++t) {
            int rb = wc * 64 + t * 16 + m;
            bg[t] = *(const bf16frag*)&Bs[rb * 32 + (q ^ ((rb >> 1) & 3)) * 8];
        }
        #pragma unroll
        for (int s16 = 0; s16 < 2; ++s16) {      // s16=0: hi_a, s16=1: lo_a
            bf16frag af[4];
            #pragma unroll
            for (int t = 0; t < 4; ++t) {
                int ra = wr * 64 + t * 16 + m;
                af[t] = *(const bf16frag*)&As[ra * 64 + ((s16 * 4 + q) ^ (ra & 7)) * 8];
            }
            #pragma unroll
            for (int ti = 0; ti < 4; ++ti)
                #pragma unroll
                for (int tj = 0; tj < 4; ++tj)
                    acc[ti][tj] = __builtin_amdgcn_mfma_f32_16x16x32_bf16(
                        af[ti], bg[tj], acc[ti][tj], 0, 0, 0);
        }
    }

    float s = 0.0f;
    #pragma unroll
    for (int ti = 0; ti < 4; ++ti) {
        #pragma unroll
        for (int r = 0; r < 4; ++r) {
            int i = i0 + wr * 64 + ti * 16 + q * 4 + r;
            float ai = na[i];
            #pragma unroll
            for (int tj = 0; tj < 4; ++tj) {
                int j = j0 + wc * 64 + tj * 16 + m;
                float d = ai + nb[j] - 2.0f * acc[ti][tj][r];
                d = fmaxf(d, 0.0f);
                s += expf(-MMD_GAMMA * d);
            }
        }
    }
    red[tid] = s;
    __syncthreads();
    for (int st = 128; st > 0; st >>= 1) {
        if (tid < st) red[tid] += red[tid + st];
        __syncthreads();
    }
    if (tid == 0) atomicAdd(&accg[z], w * (double)red[0]);
}

// ---------------------------------------------------------------------------
__global__ void k_finalize(const double* __restrict__ acc, float* __restrict__ out) {
    const double inv = 1.0 / ((double)NP * (double)NP);
    out[0] = (float)((acc[0] + acc[1] - 2.0 * acc[2]) * inv);
}

extern "C" void kernel_launch(void* const* d_in, const int* in_sizes, int n_in,
                              void* d_out, int out_size, void* d_ws, size_t ws_size,
                              hipStream_t stream) {
    const float* x = (const float*)d_in[0];
    const float* y = (const float*)d_in[1];
    float* out = (float*)d_out;

    char* ws = (char*)d_ws;
    double* acc = (double*)ws;                        // [0,24)
    float*  b2f = (float*)(ws + 4096);                // 8KB
    float*  a2f = (float*)(ws + 12288);               // 8KB
    double* d2p = (double*)(ws + 32768);              // 1.5 MB
    float*  X   = (float*)(ws + 32768 + 1605632);
    unsigned short* Xhi = (unsigned short*)(X + (size_t)NP * CD);
    unsigned short* Xlo = Xhi + (size_t)NP * CD;
    unsigned short* Yhi = Xlo + (size_t)NP * CD;
    unsigned short* Ylo = Yhi + (size_t)NP * CD;

    hipMemsetAsync(ws, 0, 20480, stream);             // acc + b2f + a2f
    k_transpose_x<<<dim3(64, 12), 256, 0, stream>>>(x, X, Xhi, Xlo, a2f);
    k_d2_partial<<<dim3(256, NSPLIT), 256, 0, stream>>>(x, y, d2p);
    k_gather_pack_y<<<dim3(64, 12), 256, 0, stream>>>(y, d2p, Yhi, Ylo, b2f);
    k_mmd_mfma<<<NJOBS, 256, 0, stream>>>(Xhi, Xlo, Yhi, Ylo, a2f, b2f, acc);
    k_finalize<<<1, 1, 0, stream>>>(acc, out);
}

// Round 9
// 228.583 us; speedup vs baseline: 1.2196x; 1.0045x over previous
//
#include <hip/hip_runtime.h>

// Problem constants
#define NP 2048          // B*H1*W1 points
#define CD 768           // channels
#define NSPLIT 6         // channel splits for d2 partials (128 ch each)
#define NJOBS 528        // 136 XX-tri + 136 YY-tri + 256 XY tiles
#define MMD_GAMMA 0.00065f

typedef short bf16frag __attribute__((ext_vector_type(8)));
typedef float f32x4 __attribute__((ext_vector_type(4)));

#define GLD16(g, l)  __builtin_amdgcn_global_load_lds(                      \
    (const __attribute__((address_space(1))) void*)(g),                     \
    (__attribute__((address_space(3))) void*)(l), 16, 0, 0)

static __device__ inline unsigned short f2bf(float v) {
    union { float f; unsigned u; } a; a.f = v;
    unsigned r = a.u + 0x7fffu + ((a.u >> 16) & 1u);
    return (unsigned short)(r >> 16);
}
static __device__ inline float bf2f(unsigned short h) {
    union { unsigned u; float f; } a; a.u = ((unsigned)h) << 16;
    return a.f;
}

// ---------------------------------------------------------------------------
// Fused prep: blocks 0..1535 = d2 partials (memory-heavy, scheduled first);
// blocks 1536..2303 = x transpose + bf16 split pack + a2 partial norms.
// Branches are independent (disjoint outputs) -> true in-stream overlap.
__global__ __launch_bounds__(256, 4)
void k_prep(const float* __restrict__ x, const float* __restrict__ y,
            double* __restrict__ d2p,
            unsigned short* __restrict__ Xhi, unsigned short* __restrict__ Xlo,
            float* __restrict__ a2f) {
    __shared__ double redd[8][32][4];     // d2 branch (8 KB)
    __shared__ float tile[64][33];        // transpose branch (8.4 KB)
    __shared__ float sqred[8][32];
    int bid = blockIdx.x;
    int tid = threadIdx.x;

    if (bid < 1536) {
        // ---- d2 partial branch (identical math/order to round-8 kernel) ----
        int bxh = bid & 255;
        int cs  = bid >> 8;
        int b = bxh >> 7, h = bxh & 127;
        int h1 = h >> 2, i = h & 3;
        int w1 = tid & 31, cg = tid >> 5;
        int c0 = cs * 128 + cg;
        const float* yp = y + ((size_t)(b * 768 + c0) * 128 + h) * 128 + 4 * w1;
        const float* xp = x + (size_t)(b * 768 + c0) * 1024 + h1 * 32 + w1;
        double a0 = 0.0, a1 = 0.0, a2 = 0.0, a3 = 0.0;
        #pragma unroll 8
        for (int k = 0; k < 16; ++k) {
            float4 yv = *(const float4*)yp;
            float xv = *xp;
            double xd = (double)xv;
            double d0 = xd - (double)yv.x;
            double d1 = xd - (double)yv.y;
            double d2_ = xd - (double)yv.z;
            double d3 = xd - (double)yv.w;
            a0 += d0 * d0; a1 += d1 * d1; a2 += d2_ * d2_; a3 += d3 * d3;
            yp += (size_t)8 * 16384;
            xp += (size_t)8 * 1024;
        }
        redd[cg][w1][0] = a0; redd[cg][w1][1] = a1;
        redd[cg][w1][2] = a2; redd[cg][w1][3] = a3;
        __syncthreads();
        if (tid < 128) {
            int w = tid >> 2, j = tid & 3;
            double s = 0.0;
            #pragma unroll
            for (int g = 0; g < 8; ++g) s += redd[g][w][j];
            int n = b * 1024 + h1 * 32 + w;
            d2p[((size_t)cs * NP + n) * 16 + i * 4 + j] = s;
        }
    } else {
        // ---- transpose + pack branch (X float write removed: dead) ----
        int id = bid - 1536;
        int bx = id & 63;
        int c0 = (id >> 6) * 64;
        int b = bx >> 5, h1 = bx & 31;
        const float* src = x + (size_t)(b * 768 + c0) * 1024 + h1 * 32;
        #pragma unroll
        for (int p = 0; p < 8; ++p) {
            int cl = p * 8 + (tid >> 5);
            int w1 = tid & 31;
            tile[cl][w1] = src[(size_t)cl * 1024 + w1];
        }
        __syncthreads();
        int n0 = bx * 32;
        #pragma unroll
        for (int p = 0; p < 8; ++p) {
            int w1 = p * 4 + (tid >> 6);
            int c  = tid & 63;
            float v = tile[c][w1];
            size_t o = (size_t)(n0 + w1) * CD + c0 + c;
            unsigned short h = f2bf(v);
            Xhi[o] = h;
            Xlo[o] = f2bf(v - bf2f(h));
        }
        {
            int w1 = tid & 31, cseg = tid >> 5;
            float s = 0.f;
            #pragma unroll
            for (int u = 0; u < 8; ++u) {
                float v = tile[cseg * 8 + u][w1];
                s += v * v;
            }
            sqred[cseg][w1] = s;
        }
        __syncthreads();
        if (tid < 32) {
            float s = 0.f;
            #pragma unroll
            for (int g = 0; g < 8; ++g) s += sqred[g][tid];
            atomicAdd(&a2f[n0 + tid], s);
        }
    }
}

// ---------------------------------------------------------------------------
// Fused argmax + coalesced gather + bf16 pack + b2 partial norms.
__global__ __launch_bounds__(256, 4)
void k_gather_pack_y(const float* __restrict__ y, const double* __restrict__ d2p,
                     unsigned short* __restrict__ Yhi, unsigned short* __restrict__ Ylo,
                     float* __restrict__ b2f) {
    __shared__ float ytile[8][520];
    __shared__ int sOff[32];
    __shared__ float sqred[32][8];
    int bh = blockIdx.x;                // b*32 + h1
    int cs = blockIdx.y;                // 0..11, 64 channels each
    int b = bh >> 5, h1 = bh & 31;
    int tid = threadIdx.x;
    if (tid < 32) {
        int n = b * 1024 + h1 * 32 + tid;
        double s[16];
        #pragma unroll
        for (int k = 0; k < 16; ++k) s[k] = 0.0;
        for (int c = 0; c < NSPLIT; ++c) {
            #pragma unroll
            for (int k = 0; k < 16; ++k) s[k] += d2p[((size_t)c * NP + n) * 16 + k];
        }
        double best = s[0]; int bi = 0;
        #pragma unroll
        for (int k = 1; k < 16; ++k) if (s[k] > best) { best = s[k]; bi = k; }
        sOff[tid] = (bi >> 2) * 128 + 4 * tid + (bi & 3);
    }
    __syncthreads();
    int c_loc = tid & 7, n_loc = tid >> 3;
    int ch_s = tid >> 5, part = tid & 31;
    int off = sOff[n_loc];
    int n = b * 1024 + h1 * 32 + n_loc;
    float sq = 0.f;
    for (int kt = 0; kt < 8; ++kt) {
        int c0 = cs * 64 + kt * 8;
        __syncthreads();
        const float* src = y + ((size_t)(b * 768 + c0 + ch_s) * 128 + 4 * h1) * 128;
        #pragma unroll
        for (int u = 0; u < 4; ++u)
            *(float4*)&ytile[ch_s][u * 128 + part * 4] = *(const float4*)(src + u * 128 + part * 4);
        __syncthreads();
        float v = ytile[c_loc][off];
        unsigned short h = f2bf(v);
        size_t o = (size_t)n * CD + c0 + c_loc;
        Yhi[o] = h;
        Ylo[o] = f2bf(v - bf2f(h));
        sq += v * v;
    }
    sqred[n_loc][c_loc] = sq;
    __syncthreads();
    if (tid < 32) {
        float s = 0.f;
        #pragma unroll
        for (int g = 0; g < 8; ++g) s += sqred[tid][g];
        atomicAdd(&b2f[b * 1024 + h1 * 32 + tid], s);
    }
}

// ---------------------------------------------------------------------------
// MFMA Gram + exp-sum, 2-term split (Gram = a . hi_b), with embedded
// finalize: last block to arrive (device-scope done-counter) computes the
// output scalar via atomic-RMW reads of accg (cross-XCD coherent).
__global__ __launch_bounds__(256, 3)
void k_mmd_mfma(const unsigned short* __restrict__ Xhi, const unsigned short* __restrict__ Xlo,
                const unsigned short* __restrict__ Yhi, const unsigned short* __restrict__ Ylo,
                const float* __restrict__ a2, const float* __restrict__ b2,
                double* __restrict__ accg, unsigned int* __restrict__ done,
                float* __restrict__ out) {
    __shared__ unsigned short As[128 * 64];   // 16 KB
    __shared__ unsigned short Bs[128 * 32];   // 8 KB
    __shared__ float red[256];

    int id = blockIdx.x;
    int z, bx, by;
    double w = 1.0;
    if (id < 272) {
        z = (id < 136) ? 0 : 1;
        if (id >= 136) id -= 136;
        int r = 0;
        while (id >= 16 - r) { id -= 16 - r; ++r; }
        by = r; bx = r + id;
        if (bx != by) w = 2.0;
    } else {
        z = 2; id -= 272;
        bx = id & 15; by = id >> 4;
    }
    const unsigned short* AH = (z == 1) ? Yhi : Xhi;
    const unsigned short* AL = (z == 1) ? Ylo : Xlo;
    const unsigned short* BH = (z == 0) ? Xhi : Yhi;
    const float* na = (z == 1) ? b2 : a2;
    const float* nb = (z == 0) ? a2 : b2;
    int i0 = by * 128, j0 = bx * 128;

    int tid = threadIdx.x;
    int lane = tid & 63;
    int wv = tid >> 6;
    int wr = wv >> 1, wc = wv & 1;
    int m = lane & 15, q = lane >> 4;
    int lrow = lane >> 3, lchunk = lane & 7;   // A staging: 8 rows x 8 chunks
    int lrowB = lane >> 2, lchunkB = lane & 3; // B staging: 16 rows x 4 chunks

    f32x4 acc[4][4] = {};

    for (int wnd = 0; wnd < 24; ++wnd) {
        int c0 = wnd * 32;
        __syncthreads();
        #pragma unroll
        for (int s = 0; s < 4; ++s) {
            int r0 = s * 32 + wv * 8;
            int r  = r0 + lrow;
            int cg = lchunk ^ (r & 7);
            const unsigned short* srcA =
                (cg < 4 ? AH : AL) + (size_t)(i0 + r) * CD + c0 + (cg & 3) * 8;
            GLD16(srcA, &As[r0 * 64]);
        }
        #pragma unroll
        for (int s = 0; s < 2; ++s) {
            int r0 = s * 64 + wv * 16;
            int r  = r0 + lrowB;
            int cg = lchunkB ^ ((r >> 1) & 3);
            GLD16(BH + (size_t)(j0 + r) * CD + c0 + cg * 8, &Bs[r0 * 32]);
        }
        __syncthreads();
        bf16frag bg[4];
        #pragma unroll
        for (int t = 0; t < 4; ++t) {
            int rb = wc * 64 + t * 16 + m;
            bg[t] = *(const bf16frag*)&Bs[rb * 32 + (q ^ ((rb >> 1) & 3)) * 8];
        }
        #pragma unroll
        for (int s16 = 0; s16 < 2; ++s16) {      // s16=0: hi_a, s16=1: lo_a
            bf16frag af[4];
            #pragma unroll
            for (int t = 0; t < 4; ++t) {
                int ra = wr * 64 + t * 16 + m;
                af[t] = *(const bf16frag*)&As[ra * 64 + ((s16 * 4 + q) ^ (ra & 7)) * 8];
            }
            #pragma unroll
            for (int ti = 0; ti < 4; ++ti)
                #pragma unroll
                for (int tj = 0; tj < 4; ++tj)
                    acc[ti][tj] = __builtin_amdgcn_mfma_f32_16x16x32_bf16(
                        af[ti], bg[tj], acc[ti][tj], 0, 0, 0);
        }
    }

    float s = 0.0f;
    #pragma unroll
    for (int ti = 0; ti < 4; ++ti) {
        #pragma unroll
        for (int r = 0; r < 4; ++r) {
            int i = i0 + wr * 64 + ti * 16 + q * 4 + r;
            float ai = na[i];
            #pragma unroll
            for (int tj = 0; tj < 4; ++tj) {
                int j = j0 + wc * 64 + tj * 16 + m;
                float d = ai + nb[j] - 2.0f * acc[ti][tj][r];
                d = fmaxf(d, 0.0f);
                s += expf(-MMD_GAMMA * d);
            }
        }
    }
    red[tid] = s;
    __syncthreads();
    for (int st = 128; st > 0; st >>= 1) {
        if (tid < st) red[tid] += red[tid + st];
        __syncthreads();
    }
    if (tid == 0) {
        atomicAdd(&accg[z], w * (double)red[0]);
        __threadfence();                           // accg visible before done++
        unsigned int d = atomicAdd(done, 1u);
        if (d == (unsigned int)(NJOBS - 1)) {      // last block finalizes
            double kxx = atomicAdd(&accg[0], 0.0); // atomic-RMW read: coherent
            double kyy = atomicAdd(&accg[1], 0.0);
            double kxy = atomicAdd(&accg[2], 0.0);
            const double inv = 1.0 / ((double)NP * (double)NP);
            out[0] = (float)((kxx + kyy - 2.0 * kxy) * inv);
        }
    }
}

extern "C" void kernel_launch(void* const* d_in, const int* in_sizes, int n_in,
                              void* d_out, int out_size, void* d_ws, size_t ws_size,
                              hipStream_t stream) {
    const float* x = (const float*)d_in[0];
    const float* y = (const float*)d_in[1];
    float* out = (float*)d_out;

    char* ws = (char*)d_ws;
    double*       acc  = (double*)ws;                 // [0,24)
    unsigned int* done = (unsigned int*)(ws + 64);    // 4B
    float*  b2f = (float*)(ws + 4096);                // 8KB
    float*  a2f = (float*)(ws + 12288);               // 8KB
    double* d2p = (double*)(ws + 32768);              // 1.5 MB
    unsigned short* Xhi = (unsigned short*)(ws + 32768 + 1605632);
    unsigned short* Xlo = Xhi + (size_t)NP * CD;
    unsigned short* Yhi = Xlo + (size_t)NP * CD;
    unsigned short* Ylo = Yhi + (size_t)NP * CD;

    hipMemsetAsync(ws, 0, 20480, stream);             // acc + done + b2f + a2f
    k_prep<<<2304, 256, 0, stream>>>(x, y, d2p, Xhi, Xlo, a2f);
    k_gather_pack_y<<<dim3(64, 12), 256, 0, stream>>>(y, d2p, Yhi, Ylo, b2f);
    k_mmd_mfma<<<NJOBS, 256, 0, stream>>>(Xhi, Xlo, Yhi, Ylo, a2f, b2f, acc, done, out);
}